// Round 2
// baseline (474.240 us; speedup 1.0000x reference)
//
#include <hip/hip_runtime.h>
#include <math.h>

#define NBb 16
#define NTt 50
#define NAa 5
#define NHh 128
#define NWw 128
#define NCc 20
#define NCH 26                       // 6 + NC channels
#define NCELL (NBb*NAa*NHh*NWw)      // 1,310,720 cells
#define NREC  (NBb*NTt)              // 800 records
#define NSLOT 6                      // max list entries per record (5 ign + 1 mask)
#define NLIST (NREC*NSLOT)           // 4800 fixed list slots
#define SCALE_F 16.0f
#define IGNORE_THRES_F 0.5f
#define BAD_CONF_WEIGHT_F 1.25f
#define PI_F 3.14159265358979323846f

// ws layout (32-bit units):
//  [12]                done counter (uint) for k_main last-block epilogue
//  [16 .. 16+256)      16 accumulator copies x 16 floats (11 used per copy)
//  [272 .. 272+4800)   rec: tx,ty,tw,th,tr (float[NREC] each) + tlab (int[NREC])
//  [5072 .. 5072+4800) list: 6 slots per record; sentinel 0xFFFFFFFF = empty
//  [16384 .. +NCELL)   status grid — NEVER ZEROED (poison-tolerant encoding)
#define DONE_IDX 12
#define NCOPY 16
#define ACC_OFF 16
#define REC_OFF 272
#define LIST_OFF 5072
#define STATUS_OFF 16384

// status-cell encoding (robust to ANY initial fill pattern):
//   mask rec r : 0x3FFFFFFF - r   (r < 800; higher rec wins via min; beats ignore)
//   ignore     : 0x7FFFFFFF
//   claimed    : 0xFFFFFFFF
// Anything not in {mask range, ignore} is "unmarked" (poison). Marks are
// installed with a CAS loop so the initial value never matters; unlisted
// cells are never read.
#define MARK_IGN 0x7FFFFFFFu
#define MARK_MASK_BASE 0x3FFFFFFFu
#define CLAIMED 0xFFFFFFFFu

__device__ __forceinline__ bool is_mark(unsigned u) {
  return (u >= (MARK_MASK_BASE - (NREC - 1)) && u <= MARK_MASK_BASE) || (u == MARK_IGN);
}

// install min-combined mark regardless of initial (poisoned) contents
__device__ __forceinline__ void mark_cell(unsigned* addr, unsigned val) {
  unsigned cur = *addr;
  while (true) {
    unsigned desired = is_mark(cur) ? (cur < val ? cur : val) : val;
    if (desired == cur) break;                 // existing mark already wins
    unsigned old = atomicCAS(addr, cur, desired);
    if (old == cur) break;
    cur = old;
  }
}

__device__ __forceinline__ float inv_tanh_f(float y) {
  if (y <= -1.0f) return -2.0f;
  if (y >= 1.0f)  return  2.0f;
  float ys = fminf(fmaxf(y, -1.0f + 1e-6f), 1.0f - 1e-6f);
  return 0.5f * logf((1.0f + ys) / (1.0f - ys));
}

// softplus(z) = max(z,0) + log1p(exp(-|z|))  == BCE(z, target=0)
__device__ __forceinline__ float softplus_f(float z) {
  return fmaxf(z, 0.0f) + log1pf(expf(-fabsf(z)));
}

// Prep: zero the (small) header, write per-record targets, mark status cells,
// fill fixed list slots. No status-grid zeroing needed (see encoding above).
__global__ void k_prep(const float* __restrict__ tgt,
                       const int* __restrict__ tsz,
                       const float* __restrict__ anch,
                       float* __restrict__ ws) {
  int tid = blockIdx.x * blockDim.x + threadIdx.x;
  unsigned* wsu = (unsigned*)ws;
  if (tid < ACC_OFF + NCOPY*16) wsu[tid] = 0u;   // accumulators + done counter
  if (tid >= NREC) return;

  unsigned* list = wsu + LIST_OFF;
  #pragma unroll
  for (int s = 0; s < NSLOT; ++s) list[tid*NSLOT + s] = CLAIMED;  // empty sentinel

  int b = tid / NTt, t = tid % NTt;

  float aw[NAa], ah[NAa], ar[NAa], ahw[NAa], ap[NAa][8];
  for (int a = 0; a < NAa; ++a) {
    aw[a] = anch[a*3+0] / SCALE_F;
    ah[a] = anch[a*3+1] / SCALE_F;
    ar[a] = anch[a*3+2];
    float cr = cosf(ar[a]), sr = sinf(ar[a]);
    ap[a][0] = -cr*aw[a]; ap[a][1] =  sr*aw[a];
    ap[a][2] =  cr*aw[a]; ap[a][3] = -sr*aw[a];
    ap[a][4] = -sr*ah[a]; ap[a][5] = -cr*ah[a];
    ap[a][6] =  sr*ah[a]; ap[a][7] =  cr*ah[a];
    ahw[a] = (ah[a] + aw[a]) * 0.5f;
  }

  const float* row = tgt + (size_t)tid * (13 + NCc);
  float gx = row[0] / SCALE_F;
  float gy = row[1] / SCALE_F;
  float gr = row[2];
  float gh = row[3] / SCALE_F;
  float gw = row[4] / SCALE_F;
  bool valid = (t < tsz[b]) && (gw != 0.0f) && (gh != 0.0f);
  if (!valid) return;

  int gi = (int)gx; gi = min(max(gi, 0), NWw - 1);
  int gj = (int)gy; gj = min(max(gj, 0), NHh - 1);

  float cp[8];
  for (int k = 0; k < 8; ++k)
    cp[k] = row[5 + k] / SCALE_F - ((k & 1) ? gy : gx);

  float bestd = 1e30f; int best = 0; unsigned ignm = 0;
  for (int a = 0; a < NAa; ++a) {
    float dn = 0.0f;
    for (int p = 0; p < 8; p += 2) {
      float dx = cp[p]   - ap[a][p];
      float dy = cp[p+1] - ap[a][p+1];
      dn += sqrtf(dx*dx + dy*dy);
    }
    float nm = ((gh + gw) * 0.5f + ahw[a]) * 0.5f;
    float d = dn / nm; d = d * d;
    if (d < IGNORE_THRES_F) ignm |= (1u << a);
    if (d < bestd) { bestd = d; best = a; }
  }

  unsigned* status = wsu + STATUS_OFF;
  int cellbase = ((b * NAa) * NHh + gj) * NWw + gi;
  int nslot = 0;
  for (int a = 0; a < NAa; ++a)
    if ((ignm >> a) & 1u) {
      int cell = cellbase + a * NHh * NWw;
      mark_cell(&status[cell], MARK_IGN);
      list[tid*NSLOT + nslot++] = (unsigned)cell;
    }
  {
    int cell = cellbase + best * NHh * NWw;
    // mask mark: smaller value = higher rec wins; mask always beats ignore
    mark_cell(&status[cell], MARK_MASK_BASE - (unsigned)tid);
    if (!((ignm >> best) & 1u))
      list[tid*NSLOT + nslot++] = (unsigned)cell;
  }

  float txv = inv_tanh_f(gx - ((float)gi + 0.5f));
  float tyv = inv_tanh_f(gy - ((float)gj + 0.5f));
  float rd = gr - ar[best];
  if (rd > PI_F) rd -= 2.0f * PI_F;
  else if (rd < -PI_F) rd += 2.0f * PI_F;
  float trv = inv_tanh_f(rd / (PI_F * 0.5f));
  float twv = logf(gw / aw[best] + 1e-16f);
  float thv = logf(gh / ah[best] + 1e-16f);
  int tlab = 0; float bm = row[13];
  for (int c = 1; c < NCc; ++c)
    if (row[13 + c] > bm) { bm = row[13 + c]; tlab = c; }

  float* rec = ws + REC_OFF;
  rec[0*NREC + tid] = txv;
  rec[1*NREC + tid] = tyv;
  rec[2*NREC + tid] = twv;
  rec[3*NREC + tid] = thv;
  rec[4*NREC + tid] = trv;
  ((int*)rec)[5*NREC + tid] = tlab;
}

#define MAIN_GRID 2048
#define MAIN_BLK  256
#define MAIN_THREADS (MAIN_GRID*MAIN_BLK)   // 524,288
static_assert(2*MAIN_THREADS <= NCELL && 3*MAIN_THREADS >= NCELL, "phase-1 tiling");

// Fused: conf stream + list corrections + last-block finalize.
__global__ void __launch_bounds__(MAIN_BLK, 4) k_main(const float* __restrict__ pred,
                                                      float* __restrict__ ws,
                                                      float* __restrict__ out) {
  unsigned* wsu = (unsigned*)ws;
  unsigned* status = wsu + STATUS_OFF;
  const unsigned* list = wsu + LIST_OFF;
  const float* rec = ws + REC_OFF;
  int t = blockIdx.x * MAIN_BLK + threadIdx.x;

  // ---- Phase 1: softplus(conf) over all cells, 2-3 batched loads/thread ----
  float z0 = pred[(size_t)t * NCH];
  float z1 = pred[(size_t)(t + MAIN_THREADS) * NCH];
  bool h2 = t < (NCELL - 2*MAIN_THREADS);
  float z2 = h2 ? pred[(size_t)(t + 2*MAIN_THREADS) * NCH] : 0.0f;
  float acc = softplus_f(z0) + softplus_f(z1);
  if (h2) acc += softplus_f(z2);

  // ---- Phase 2: corrections for listed cells (first 19 blocks only) ----
  float sub = 0.0f, cnb = 0.0f, obj = 0.0f;
  float sx = 0.0f, sy = 0.0f, sw = 0.0f, sh = 0.0f, sr = 0.0f;
  float scls = 0.0f, cm = 0.0f;

  if (t < NLIST) {
    unsigned cell = list[t];
    if (cell < (unsigned)NCELL) {
      unsigned st = atomicExch(&status[cell], CLAIMED);  // claim; dedups duplicates
      if (is_mark(st)) {
        const float* cpt = pred + (size_t)cell * NCH;
        float z = cpt[0];
        sub = softplus_f(z);
        cnb = 1.0f;
        if (st != MARK_IGN) {
          int r = (int)(MARK_MASK_BASE - st);
          obj = softplus_f(z) - z;               // BCE(z, target=1)
          float dx = cpt[1] - rec[0*NREC + r];
          float dy = cpt[2] - rec[1*NREC + r];
          float dr = cpt[3] - rec[4*NREC + r];
          float dh = cpt[4] - rec[3*NREC + r];
          float dw = cpt[5] - rec[2*NREC + r];
          sx = dx*dx; sy = dy*dy; sw = dw*dw; sh = dh*dh; sr = dr*dr;
          int tlab = ((const int*)rec)[5*NREC + r];
          float m = cpt[6];
          for (int c = 1; c < NCc; ++c) m = fmaxf(m, cpt[6 + c]);
          float s = 0.0f;
          for (int c = 0; c < NCc; ++c) s += expf(cpt[6 + c] - m);
          scls = (m + logf(s)) - cpt[6 + tlab];
          cm = 1.0f;
        }
      }
    }
  }

  // ---- block reduction: 11 partials, shfl within wave then LDS across 4 waves ----
  float vals[11] = {acc, sub, cnb, obj, sx, sy, sw, sh, sr, scls, cm};
  __shared__ float red[4][11];
  int wid = threadIdx.x >> 6, lane = threadIdx.x & 63;
  #pragma unroll
  for (int k = 0; k < 11; ++k) {
    float v = vals[k];
    for (int off = 32; off; off >>= 1) v += __shfl_down(v, off, 64);
    if (lane == 0) red[wid][k] = v;
  }
  __syncthreads();
  // spread contention across 16 accumulator copies
  int copy = blockIdx.x & (NCOPY - 1);
  if (threadIdx.x < 11) {
    float v = red[0][threadIdx.x] + red[1][threadIdx.x]
            + red[2][threadIdx.x] + red[3][threadIdx.x];
    if (v != 0.0f) atomicAdd(&ws[ACC_OFF + copy*16 + threadIdx.x], v);
  }

  // ---- last-block finalize ----
  __threadfence();            // release our partial atomicAdds (each thread its own)
  __syncthreads();            // ensure all 11 adder-threads fenced before count
  __shared__ int lastFlag;
  if (threadIdx.x == 0) {
    unsigned old = atomicAdd(&wsu[DONE_IDX], 1u);
    lastFlag = (old == MAIN_GRID - 1) ? 1 : 0;
  }
  __syncthreads();
  if (!lastFlag) return;

  __shared__ float part[NCOPY][11];
  if (threadIdx.x < NCOPY*11) {
    int c = threadIdx.x / 11, k = threadIdx.x % 11;
    // coherent read-back (atomic RMW with 0 add)
    part[c][k] = atomicAdd(&ws[ACC_OFF + c*16 + k], 0.0f);
  }
  __syncthreads();
  if (threadIdx.x == 0) {
    float tot[11];
    #pragma unroll
    for (int k = 0; k < 11; ++k) {
      float v = 0.0f;
      for (int c = 0; c < NCOPY; ++c) v += part[c][k];
      tot[k] = v;
    }
    float acc_bg = tot[0] - tot[1];
    float cnt_bg = (float)NCELL - tot[2];
    float db = fmaxf(cnt_bg, 1.0f);
    float dm = fmaxf(tot[10], 1.0f);
    float loss_conf = BAD_CONF_WEIGHT_F * (acc_bg / db) + tot[3] / dm;
    out[0] = (tot[4] + tot[5] + tot[6] + tot[7] + tot[8] + tot[9]) / dm + loss_conf;
  }
}

extern "C" void kernel_launch(void* const* d_in, const int* in_sizes, int n_in,
                              void* d_out, int out_size, void* d_ws, size_t ws_size,
                              hipStream_t stream) {
  const float* pred = (const float*)d_in[0];   // (16,5,128,128,26)
  const float* tgt  = (const float*)d_in[1];   // (16,50,33)
  const int*   tsz  = (const int*)d_in[2];     // (16,)
  const float* anch = (const float*)d_in[3];   // (5,3)
  float* ws = (float*)d_ws;

  k_prep<<<4, 256, 0, stream>>>(tgt, tsz, anch, ws);
  k_main<<<MAIN_GRID, MAIN_BLK, 0, stream>>>(pred, ws, (float*)d_out);
}

// Round 3
// 213.687 us; speedup vs baseline: 2.2193x; 2.2193x over previous
//
#include <hip/hip_runtime.h>
#include <math.h>

#define NBb 16
#define NTt 50
#define NAa 5
#define NHh 128
#define NWw 128
#define NCc 20
#define NCH 26                       // 6 + NC channels
#define NCELL (NBb*NAa*NHh*NWw)      // 1,310,720 cells
#define NREC  (NBb*NTt)              // 800 records
#define NSLOT 6                      // max list entries per record (5 ign + 1 mask)
#define NLIST (NREC*NSLOT)           // 4800 fixed list slots
#define SCALE_F 16.0f
#define IGNORE_THRES_F 0.5f
#define BAD_CONF_WEIGHT_F 1.25f
#define PI_F 3.14159265358979323846f

// ws layout (32-bit units):
//  [16 .. 16+256)      16 accumulator copies x 16 floats (11 used per copy)
//  [272 .. 272+4800)   rec: tx,ty,tw,th,tr (float[NREC] each) + tlab (int[NREC])
//  [5072 .. 5072+4800) list: 6 slots per record; sentinel 0xFFFFFFFF = empty
//  [16384 .. +NCELL)   status grid — NEVER ZEROED (poison-tolerant encoding)
#define NCOPY 16
#define ACC_OFF 16
#define REC_OFF 272
#define LIST_OFF 5072
#define STATUS_OFF 16384

// status-cell encoding (robust to ANY initial fill pattern):
//   mask rec r : 0x3FFFFFFF - r   (r < 800; higher rec wins via min; beats ignore)
//   ignore     : 0x7FFFFFFF
//   claimed    : 0xFFFFFFFF
// Anything not in {mask range, ignore} is "unmarked" (poison). Marks are
// installed with a CAS loop so the initial value never matters; unlisted
// cells are never read.
#define MARK_IGN 0x7FFFFFFFu
#define MARK_MASK_BASE 0x3FFFFFFFu
#define CLAIMED 0xFFFFFFFFu

__device__ __forceinline__ bool is_mark(unsigned u) {
  return (u >= (MARK_MASK_BASE - (NREC - 1)) && u <= MARK_MASK_BASE) || (u == MARK_IGN);
}

// install min-combined mark regardless of initial (poisoned) contents
__device__ __forceinline__ void mark_cell(unsigned* addr, unsigned val) {
  unsigned cur = *addr;
  while (true) {
    unsigned desired = is_mark(cur) ? (cur < val ? cur : val) : val;
    if (desired == cur) break;                 // existing mark already wins
    unsigned old = atomicCAS(addr, cur, desired);
    if (old == cur) break;
    cur = old;
  }
}

__device__ __forceinline__ float inv_tanh_f(float y) {
  if (y <= -1.0f) return -2.0f;
  if (y >= 1.0f)  return  2.0f;
  float ys = fminf(fmaxf(y, -1.0f + 1e-6f), 1.0f - 1e-6f);
  return 0.5f * logf((1.0f + ys) / (1.0f - ys));
}

// softplus(z) = max(z,0) + log1p(exp(-|z|))  == BCE(z, target=0)
__device__ __forceinline__ float softplus_f(float z) {
  return fmaxf(z, 0.0f) + log1pf(expf(-fabsf(z)));
}

// Prep: zero the (small) header, write per-record targets, mark status cells,
// fill fixed list slots. No status-grid zeroing needed (see encoding above).
__global__ void k_prep(const float* __restrict__ tgt,
                       const int* __restrict__ tsz,
                       const float* __restrict__ anch,
                       float* __restrict__ ws) {
  int tid = blockIdx.x * blockDim.x + threadIdx.x;
  unsigned* wsu = (unsigned*)ws;
  if (tid < ACC_OFF + NCOPY*16) wsu[tid] = 0u;   // header + accumulator copies
  if (tid >= NREC) return;

  unsigned* list = wsu + LIST_OFF;
  #pragma unroll
  for (int s = 0; s < NSLOT; ++s) list[tid*NSLOT + s] = CLAIMED;  // empty sentinel

  int b = tid / NTt, t = tid % NTt;

  float aw[NAa], ah[NAa], ar[NAa], ahw[NAa], ap[NAa][8];
  for (int a = 0; a < NAa; ++a) {
    aw[a] = anch[a*3+0] / SCALE_F;
    ah[a] = anch[a*3+1] / SCALE_F;
    ar[a] = anch[a*3+2];
    float cr = cosf(ar[a]), sr = sinf(ar[a]);
    ap[a][0] = -cr*aw[a]; ap[a][1] =  sr*aw[a];
    ap[a][2] =  cr*aw[a]; ap[a][3] = -sr*aw[a];
    ap[a][4] = -sr*ah[a]; ap[a][5] = -cr*ah[a];
    ap[a][6] =  sr*ah[a]; ap[a][7] =  cr*ah[a];
    ahw[a] = (ah[a] + aw[a]) * 0.5f;
  }

  const float* row = tgt + (size_t)tid * (13 + NCc);
  float gx = row[0] / SCALE_F;
  float gy = row[1] / SCALE_F;
  float gr = row[2];
  float gh = row[3] / SCALE_F;
  float gw = row[4] / SCALE_F;
  bool valid = (t < tsz[b]) && (gw != 0.0f) && (gh != 0.0f);
  if (!valid) return;

  int gi = (int)gx; gi = min(max(gi, 0), NWw - 1);
  int gj = (int)gy; gj = min(max(gj, 0), NHh - 1);

  float cp[8];
  for (int k = 0; k < 8; ++k)
    cp[k] = row[5 + k] / SCALE_F - ((k & 1) ? gy : gx);

  float bestd = 1e30f; int best = 0; unsigned ignm = 0;
  for (int a = 0; a < NAa; ++a) {
    float dn = 0.0f;
    for (int p = 0; p < 8; p += 2) {
      float dx = cp[p]   - ap[a][p];
      float dy = cp[p+1] - ap[a][p+1];
      dn += sqrtf(dx*dx + dy*dy);
    }
    float nm = ((gh + gw) * 0.5f + ahw[a]) * 0.5f;
    float d = dn / nm; d = d * d;
    if (d < IGNORE_THRES_F) ignm |= (1u << a);
    if (d < bestd) { bestd = d; best = a; }
  }

  unsigned* status = wsu + STATUS_OFF;
  int cellbase = ((b * NAa) * NHh + gj) * NWw + gi;
  int nslot = 0;
  for (int a = 0; a < NAa; ++a)
    if ((ignm >> a) & 1u) {
      int cell = cellbase + a * NHh * NWw;
      mark_cell(&status[cell], MARK_IGN);
      list[tid*NSLOT + nslot++] = (unsigned)cell;
    }
  {
    int cell = cellbase + best * NHh * NWw;
    // mask mark: smaller value = higher rec wins; mask always beats ignore
    mark_cell(&status[cell], MARK_MASK_BASE - (unsigned)tid);
    if (!((ignm >> best) & 1u))
      list[tid*NSLOT + nslot++] = (unsigned)cell;
  }

  float txv = inv_tanh_f(gx - ((float)gi + 0.5f));
  float tyv = inv_tanh_f(gy - ((float)gj + 0.5f));
  float rd = gr - ar[best];
  if (rd > PI_F) rd -= 2.0f * PI_F;
  else if (rd < -PI_F) rd += 2.0f * PI_F;
  float trv = inv_tanh_f(rd / (PI_F * 0.5f));
  float twv = logf(gw / aw[best] + 1e-16f);
  float thv = logf(gh / ah[best] + 1e-16f);
  int tlab = 0; float bm = row[13];
  for (int c = 1; c < NCc; ++c)
    if (row[13 + c] > bm) { bm = row[13 + c]; tlab = c; }

  float* rec = ws + REC_OFF;
  rec[0*NREC + tid] = txv;
  rec[1*NREC + tid] = tyv;
  rec[2*NREC + tid] = twv;
  rec[3*NREC + tid] = thv;
  rec[4*NREC + tid] = trv;
  ((int*)rec)[5*NREC + tid] = tlab;
}

#define MAIN_GRID 1024
#define MAIN_BLK  256
#define MAIN_STRIDE (MAIN_GRID*MAIN_BLK)   // 262,144; NCELL == 5*MAIN_STRIDE exactly
static_assert(NCELL == 5 * MAIN_STRIDE, "conf loop unroll assumes 5 cells/thread");

// Streaming + correction kernel. NO fences, NO in-kernel finalize (round-2's
// per-wave __threadfence lowered to L2 writeback/invalidate storms: 332 us).
// Phase 1: each thread reads ONLY the conf channel (stride-26 dword gather)
//          of exactly 5 cells — 5 independent loads in flight per thread.
// Phase 2: first 19 blocks walk the fixed list slots; claim each cell once
//          via atomicExch, accumulate corrections + masked losses.
__global__ void __launch_bounds__(MAIN_BLK) k_main(const float* __restrict__ pred,
                                                   float* __restrict__ ws) {
  unsigned* wsu = (unsigned*)ws;
  unsigned* status = wsu + STATUS_OFF;
  const unsigned* list = wsu + LIST_OFF;
  const float* rec = ws + REC_OFF;
  int t = blockIdx.x * MAIN_BLK + threadIdx.x;

  // ---- Phase 1: softplus(conf) over all cells, 5 cells/thread, unrolled ----
  float acc = 0.0f;
  #pragma unroll
  for (int k = 0; k < 5; ++k) {
    float z = pred[(size_t)(t + k * MAIN_STRIDE) * NCH];
    acc += softplus_f(z);
  }

  // ---- Phase 2: corrections for listed cells (first 19 blocks only) ----
  float sub = 0.0f, cnb = 0.0f, obj = 0.0f;
  float sx = 0.0f, sy = 0.0f, sw = 0.0f, sh = 0.0f, sr = 0.0f;
  float scls = 0.0f, cm = 0.0f;

  if (t < NLIST) {
    unsigned cell = list[t];
    if (cell < (unsigned)NCELL) {
      unsigned st = atomicExch(&status[cell], CLAIMED);  // claim; dedups duplicates
      if (is_mark(st)) {
        const float* cpt = pred + (size_t)cell * NCH;
        float z = cpt[0];
        sub = softplus_f(z);
        cnb = 1.0f;
        if (st != MARK_IGN) {
          int r = (int)(MARK_MASK_BASE - st);
          obj = softplus_f(z) - z;               // BCE(z, target=1)
          float dx = cpt[1] - rec[0*NREC + r];
          float dy = cpt[2] - rec[1*NREC + r];
          float dr = cpt[3] - rec[4*NREC + r];
          float dh = cpt[4] - rec[3*NREC + r];
          float dw = cpt[5] - rec[2*NREC + r];
          sx = dx*dx; sy = dy*dy; sw = dw*dw; sh = dh*dh; sr = dr*dr;
          int tlab = ((const int*)rec)[5*NREC + r];
          float m = cpt[6];
          for (int c = 1; c < NCc; ++c) m = fmaxf(m, cpt[6 + c]);
          float s = 0.0f;
          for (int c = 0; c < NCc; ++c) s += expf(cpt[6 + c] - m);
          scls = (m + logf(s)) - cpt[6 + tlab];
          cm = 1.0f;
        }
      }
    }
  }

  // ---- block reduction: 11 partials, shfl within wave then LDS across 4 waves ----
  float vals[11] = {acc, sub, cnb, obj, sx, sy, sw, sh, sr, scls, cm};
  __shared__ float red[4][11];
  int wid = threadIdx.x >> 6, lane = threadIdx.x & 63;
  #pragma unroll
  for (int k = 0; k < 11; ++k) {
    float v = vals[k];
    for (int off = 32; off; off >>= 1) v += __shfl_down(v, off, 64);
    if (lane == 0) red[wid][k] = v;
  }
  __syncthreads();
  // spread same-address contention across 16 accumulator copies
  int copy = blockIdx.x & (NCOPY - 1);
  if (threadIdx.x < 11) {
    float v = red[0][threadIdx.x] + red[1][threadIdx.x]
            + red[2][threadIdx.x] + red[3][threadIdx.x];
    if (v != 0.0f) atomicAdd(&ws[ACC_OFF + copy*16 + threadIdx.x], v);
  }
}

// Combine the 16x11 accumulators into the scalar loss (kernel boundary
// provides the release/acquire ordering — no fences needed).
__global__ void k_fin(const float* __restrict__ ws, float* __restrict__ out) {
  __shared__ float tot[11];
  if (threadIdx.x < 11) {
    float v = 0.0f;
    for (int c = 0; c < NCOPY; ++c) v += ws[ACC_OFF + c*16 + threadIdx.x];
    tot[threadIdx.x] = v;
  }
  __syncthreads();
  if (threadIdx.x == 0) {
    float acc_bg = tot[0] - tot[1];
    float cnt_bg = (float)NCELL - tot[2];
    float db = fmaxf(cnt_bg, 1.0f);
    float dm = fmaxf(tot[10], 1.0f);
    float loss_conf = BAD_CONF_WEIGHT_F * (acc_bg / db) + tot[3] / dm;
    out[0] = (tot[4] + tot[5] + tot[6] + tot[7] + tot[8] + tot[9]) / dm + loss_conf;
  }
}

extern "C" void kernel_launch(void* const* d_in, const int* in_sizes, int n_in,
                              void* d_out, int out_size, void* d_ws, size_t ws_size,
                              hipStream_t stream) {
  const float* pred = (const float*)d_in[0];   // (16,5,128,128,26)
  const float* tgt  = (const float*)d_in[1];   // (16,50,33)
  const int*   tsz  = (const int*)d_in[2];     // (16,)
  const float* anch = (const float*)d_in[3];   // (5,3)
  float* ws = (float*)d_ws;

  k_prep<<<4, 256, 0, stream>>>(tgt, tsz, anch, ws);
  k_main<<<MAIN_GRID, MAIN_BLK, 0, stream>>>(pred, ws);
  k_fin<<<1, 64, 0, stream>>>(ws, (float*)d_out);
}

// Round 4
// 209.879 us; speedup vs baseline: 2.2596x; 1.0181x over previous
//
#include <hip/hip_runtime.h>
#include <math.h>

#define NBb 16
#define NTt 50
#define NAa 5
#define NHh 128
#define NWw 128
#define NCc 20
#define NCH 26                       // 6 + NC channels
#define NCELL (NBb*NAa*NHh*NWw)      // 1,310,720 cells
#define NFLAT (NCELL*NCH)            // 34,078,720 floats
#define NQ4   (NFLAT/4)              // 8,519,680 float4s (exact)
#define NREC  (NBb*NTt)              // 800 records
#define NSLOT 6                      // max list entries per record (5 ign + 1 mask)
#define NLIST (NREC*NSLOT)           // 4800 fixed list slots
#define SCALE_F 16.0f
#define IGNORE_THRES_F 0.5f
#define BAD_CONF_WEIGHT_F 1.25f
#define PI_F 3.14159265358979323846f

// ws layout (32-bit units):
//  [16 .. 16+256)      16 accumulator copies x 16 floats (11 used per copy)
//  [272 .. 272+4800)   rec: tx,ty,tw,th,tr (float[NREC] each) + tlab (int[NREC])
//  [5072 .. 5072+4800) list: 6 slots per record; sentinel 0xFFFFFFFF = empty
//  [16384 .. +NCELL)   status grid — NEVER ZEROED (poison-tolerant encoding)
#define NCOPY 16
#define ACC_OFF 16
#define REC_OFF 272
#define LIST_OFF 5072
#define STATUS_OFF 16384

// status-cell encoding (robust to ANY initial fill pattern):
//   mask rec r : 0x3FFFFFFF - r   (r < 800; higher rec wins via min; beats ignore)
//   ignore     : 0x7FFFFFFF
//   claimed    : 0xFFFFFFFF
// Anything not in {mask range, ignore} is "unmarked" (poison). Marks are
// installed with a CAS loop so the initial value never matters; unlisted
// cells are never read.
#define MARK_IGN 0x7FFFFFFFu
#define MARK_MASK_BASE 0x3FFFFFFFu
#define CLAIMED 0xFFFFFFFFu

__device__ __forceinline__ bool is_mark(unsigned u) {
  return (u >= (MARK_MASK_BASE - (NREC - 1)) && u <= MARK_MASK_BASE) || (u == MARK_IGN);
}

// install min-combined mark regardless of initial (poisoned) contents
__device__ __forceinline__ void mark_cell(unsigned* addr, unsigned val) {
  unsigned cur = *addr;
  while (true) {
    unsigned desired = is_mark(cur) ? (cur < val ? cur : val) : val;
    if (desired == cur) break;                 // existing mark already wins
    unsigned old = atomicCAS(addr, cur, desired);
    if (old == cur) break;
    cur = old;
  }
}

__device__ __forceinline__ float inv_tanh_f(float y) {
  if (y <= -1.0f) return -2.0f;
  if (y >= 1.0f)  return  2.0f;
  float ys = fminf(fmaxf(y, -1.0f + 1e-6f), 1.0f - 1e-6f);
  return 0.5f * logf((1.0f + ys) / (1.0f - ys));
}

// softplus(z) = max(z,0) + log1p(exp(-|z|))  == BCE(z, target=0)
__device__ __forceinline__ float softplus_f(float z) {
  return fmaxf(z, 0.0f) + log1pf(expf(-fabsf(z)));
}

// Prep: zero the (small) header, write per-record targets, mark status cells,
// fill fixed list slots. No status-grid zeroing needed (see encoding above).
__global__ void k_prep(const float* __restrict__ tgt,
                       const int* __restrict__ tsz,
                       const float* __restrict__ anch,
                       float* __restrict__ ws) {
  int tid = blockIdx.x * blockDim.x + threadIdx.x;
  unsigned* wsu = (unsigned*)ws;
  if (tid < ACC_OFF + NCOPY*16) wsu[tid] = 0u;   // header + accumulator copies
  if (tid >= NREC) return;

  unsigned* list = wsu + LIST_OFF;
  #pragma unroll
  for (int s = 0; s < NSLOT; ++s) list[tid*NSLOT + s] = CLAIMED;  // empty sentinel

  int b = tid / NTt, t = tid % NTt;

  float aw[NAa], ah[NAa], ar[NAa], ahw[NAa], ap[NAa][8];
  for (int a = 0; a < NAa; ++a) {
    aw[a] = anch[a*3+0] / SCALE_F;
    ah[a] = anch[a*3+1] / SCALE_F;
    ar[a] = anch[a*3+2];
    float cr = cosf(ar[a]), sr = sinf(ar[a]);
    ap[a][0] = -cr*aw[a]; ap[a][1] =  sr*aw[a];
    ap[a][2] =  cr*aw[a]; ap[a][3] = -sr*aw[a];
    ap[a][4] = -sr*ah[a]; ap[a][5] = -cr*ah[a];
    ap[a][6] =  sr*ah[a]; ap[a][7] =  cr*ah[a];
    ahw[a] = (ah[a] + aw[a]) * 0.5f;
  }

  const float* row = tgt + (size_t)tid * (13 + NCc);
  float gx = row[0] / SCALE_F;
  float gy = row[1] / SCALE_F;
  float gr = row[2];
  float gh = row[3] / SCALE_F;
  float gw = row[4] / SCALE_F;
  bool valid = (t < tsz[b]) && (gw != 0.0f) && (gh != 0.0f);
  if (!valid) return;

  int gi = (int)gx; gi = min(max(gi, 0), NWw - 1);
  int gj = (int)gy; gj = min(max(gj, 0), NHh - 1);

  float cp[8];
  for (int k = 0; k < 8; ++k)
    cp[k] = row[5 + k] / SCALE_F - ((k & 1) ? gy : gx);

  float bestd = 1e30f; int best = 0; unsigned ignm = 0;
  for (int a = 0; a < NAa; ++a) {
    float dn = 0.0f;
    for (int p = 0; p < 8; p += 2) {
      float dx = cp[p]   - ap[a][p];
      float dy = cp[p+1] - ap[a][p+1];
      dn += sqrtf(dx*dx + dy*dy);
    }
    float nm = ((gh + gw) * 0.5f + ahw[a]) * 0.5f;
    float d = dn / nm; d = d * d;
    if (d < IGNORE_THRES_F) ignm |= (1u << a);
    if (d < bestd) { bestd = d; best = a; }
  }

  unsigned* status = wsu + STATUS_OFF;
  int cellbase = ((b * NAa) * NHh + gj) * NWw + gi;
  int nslot = 0;
  for (int a = 0; a < NAa; ++a)
    if ((ignm >> a) & 1u) {
      int cell = cellbase + a * NHh * NWw;
      mark_cell(&status[cell], MARK_IGN);
      list[tid*NSLOT + nslot++] = (unsigned)cell;
    }
  {
    int cell = cellbase + best * NHh * NWw;
    // mask mark: smaller value = higher rec wins; mask always beats ignore
    mark_cell(&status[cell], MARK_MASK_BASE - (unsigned)tid);
    if (!((ignm >> best) & 1u))
      list[tid*NSLOT + nslot++] = (unsigned)cell;
  }

  float txv = inv_tanh_f(gx - ((float)gi + 0.5f));
  float tyv = inv_tanh_f(gy - ((float)gj + 0.5f));
  float rd = gr - ar[best];
  if (rd > PI_F) rd -= 2.0f * PI_F;
  else if (rd < -PI_F) rd += 2.0f * PI_F;
  float trv = inv_tanh_f(rd / (PI_F * 0.5f));
  float twv = logf(gw / aw[best] + 1e-16f);
  float thv = logf(gh / ah[best] + 1e-16f);
  int tlab = 0; float bm = row[13];
  for (int c = 1; c < NCc; ++c)
    if (row[13 + c] > bm) { bm = row[13 + c]; tlab = c; }

  float* rec = ws + REC_OFF;
  rec[0*NREC + tid] = txv;
  rec[1*NREC + tid] = tyv;
  rec[2*NREC + tid] = twv;
  rec[3*NREC + tid] = thv;
  rec[4*NREC + tid] = trv;
  ((int*)rec)[5*NREC + tid] = tlab;
}

#define MAIN_BLK  256
#define TILE_Q4   (MAIN_BLK*13)             // 3328 float4s per block tile
#define MAIN_GRID (NQ4 / TILE_Q4)           // 2560 blocks, exact
static_assert(MAIN_GRID * TILE_Q4 == NQ4, "tile decomposition must be exact");

// Streaming + correction kernel.
// Phase 1: fully-coalesced float4 stream of the WHOLE tensor (the stride-104
//          dword gather was latency/miss-concurrency-bound at ~1 TB/s; the
//          coalesced stream runs at HBM rate). Block b owns float4 tile
//          [b*3328, (b+1)*3328); thread t's load k reads q = b*3328 + 256k + t.
//          q%13 = (9k + t)%13, so each thread has its conf in .x at exactly
//          k1=(39-3r)%13 and in .z at k2=(57-3r)%13 (r=t%13): compile-time
//          unrolled cndmask select, 2 softplus/thread, no mod/branch per load.
// Phase 2: first 19 blocks claim listed cells via atomicExch, accumulate
//          corrections + masked losses. No fences (round-2 lesson).
__global__ void __launch_bounds__(MAIN_BLK) k_main(const float4* __restrict__ pred4,
                                                   float* __restrict__ ws) {
  unsigned* wsu = (unsigned*)ws;
  unsigned* status = wsu + STATUS_OFF;
  const unsigned* list = wsu + LIST_OFF;
  const float* rec = ws + REC_OFF;
  const float* pred = (const float*)pred4;
  int t = blockIdx.x * MAIN_BLK + threadIdx.x;

  // ---- Phase 1: coalesced stream, branch-free conf extraction ----
  int r = threadIdx.x % 13;
  int k1 = (39 - 3*r) % 13;        // load index whose .x is a conf
  int k2 = (57 - 3*r) % 13;        // load index whose .z is a conf
  const float4* base = pred4 + (size_t)blockIdx.x * TILE_Q4 + threadIdx.x;
  float cx = 0.0f, cz = 0.0f;
  #pragma unroll
  for (int k = 0; k < 13; ++k) {
    float4 v = base[k * MAIN_BLK];
    cx = (k == k1) ? v.x : cx;
    cz = (k == k2) ? v.z : cz;
  }
  float acc = softplus_f(cx) + softplus_f(cz);

  // ---- Phase 2: corrections for listed cells (first 19 blocks only) ----
  float sub = 0.0f, cnb = 0.0f, obj = 0.0f;
  float sx = 0.0f, sy = 0.0f, sw = 0.0f, sh = 0.0f, sr = 0.0f;
  float scls = 0.0f, cm = 0.0f;

  if (t < NLIST) {
    unsigned cell = list[t];
    if (cell < (unsigned)NCELL) {
      unsigned st = atomicExch(&status[cell], CLAIMED);  // claim; dedups duplicates
      if (is_mark(st)) {
        const float* cpt = pred + (size_t)cell * NCH;
        float z = cpt[0];
        sub = softplus_f(z);
        cnb = 1.0f;
        if (st != MARK_IGN) {
          int rr = (int)(MARK_MASK_BASE - st);
          obj = softplus_f(z) - z;               // BCE(z, target=1)
          float dx = cpt[1] - rec[0*NREC + rr];
          float dy = cpt[2] - rec[1*NREC + rr];
          float dr = cpt[3] - rec[4*NREC + rr];
          float dh = cpt[4] - rec[3*NREC + rr];
          float dw = cpt[5] - rec[2*NREC + rr];
          sx = dx*dx; sy = dy*dy; sw = dw*dw; sh = dh*dh; sr = dr*dr;
          int tlab = ((const int*)rec)[5*NREC + rr];
          float m = cpt[6];
          for (int c = 1; c < NCc; ++c) m = fmaxf(m, cpt[6 + c]);
          float s = 0.0f;
          for (int c = 0; c < NCc; ++c) s += expf(cpt[6 + c] - m);
          scls = (m + logf(s)) - cpt[6 + tlab];
          cm = 1.0f;
        }
      }
    }
  }

  // ---- block reduction: 11 partials, shfl within wave then LDS across 4 waves ----
  float vals[11] = {acc, sub, cnb, obj, sx, sy, sw, sh, sr, scls, cm};
  __shared__ float red[4][11];
  int wid = threadIdx.x >> 6, lane = threadIdx.x & 63;
  #pragma unroll
  for (int k = 0; k < 11; ++k) {
    float v = vals[k];
    for (int off = 32; off; off >>= 1) v += __shfl_down(v, off, 64);
    if (lane == 0) red[wid][k] = v;
  }
  __syncthreads();
  // spread same-address contention across 16 accumulator copies
  int copy = blockIdx.x & (NCOPY - 1);
  if (threadIdx.x < 11) {
    float v = red[0][threadIdx.x] + red[1][threadIdx.x]
            + red[2][threadIdx.x] + red[3][threadIdx.x];
    if (v != 0.0f) atomicAdd(&ws[ACC_OFF + copy*16 + threadIdx.x], v);
  }
}

// Combine the 16x11 accumulators into the scalar loss (kernel boundary
// provides the release/acquire ordering — no fences needed).
__global__ void k_fin(const float* __restrict__ ws, float* __restrict__ out) {
  __shared__ float tot[11];
  if (threadIdx.x < 11) {
    float v = 0.0f;
    for (int c = 0; c < NCOPY; ++c) v += ws[ACC_OFF + c*16 + threadIdx.x];
    tot[threadIdx.x] = v;
  }
  __syncthreads();
  if (threadIdx.x == 0) {
    float acc_bg = tot[0] - tot[1];
    float cnt_bg = (float)NCELL - tot[2];
    float db = fmaxf(cnt_bg, 1.0f);
    float dm = fmaxf(tot[10], 1.0f);
    float loss_conf = BAD_CONF_WEIGHT_F * (acc_bg / db) + tot[3] / dm;
    out[0] = (tot[4] + tot[5] + tot[6] + tot[7] + tot[8] + tot[9]) / dm + loss_conf;
  }
}

extern "C" void kernel_launch(void* const* d_in, const int* in_sizes, int n_in,
                              void* d_out, int out_size, void* d_ws, size_t ws_size,
                              hipStream_t stream) {
  const float* pred = (const float*)d_in[0];   // (16,5,128,128,26)
  const float* tgt  = (const float*)d_in[1];   // (16,50,33)
  const int*   tsz  = (const int*)d_in[2];     // (16,)
  const float* anch = (const float*)d_in[3];   // (5,3)
  float* ws = (float*)d_ws;

  k_prep<<<4, 256, 0, stream>>>(tgt, tsz, anch, ws);
  k_main<<<MAIN_GRID, MAIN_BLK, 0, stream>>>((const float4*)pred, ws);
  k_fin<<<1, 64, 0, stream>>>(ws, (float*)d_out);
}